// Round 1
// baseline (2574.369 us; speedup 1.0000x reference)
//
#include <hip/hip_runtime.h>

#define N_NODES 40000
#define N_EDGES 640000
#define N_REL   8
#define H_DIM   128
#define C_DIM   64

// ---------------- counts: cnt[dst*R + rel] += 1 ----------------
__global__ void count_kernel(const int* __restrict__ ei,
                             const int* __restrict__ et,
                             float* __restrict__ cnt) {
    int e = blockIdx.x * blockDim.x + threadIdx.x;
    if (e < N_EDGES) {
        int dst = ei[N_EDGES + e];
        int r   = et[e];
        atomicAdd(&cnt[dst * N_REL + r], 1.0f);
    }
}

// ---------------- conv1 scatter: h[dst] += W1[rel,src,:] / cnt ----------------
// block = 256 threads = 8 edges x 32 threads; each thread handles float4 of H
__global__ void conv1_scatter(const int* __restrict__ ei,
                              const int* __restrict__ et,
                              const float* __restrict__ W1,
                              const float* __restrict__ cnt,
                              float* __restrict__ hacc) {
    int t    = threadIdx.x;
    int sub  = t & 31;        // float4 index within H (32 * 4 = 128)
    int eloc = t >> 5;        // edge within block, 0..7
    long e = (long)blockIdx.x * 8 + eloc;
    if (e >= N_EDGES) return;
    int src = ei[e];
    int dst = ei[N_EDGES + e];
    int r   = et[e];
    float w = 1.0f / cnt[dst * N_REL + r];
    const float4* wrow = (const float4*)(W1 + ((size_t)r * N_NODES + src) * H_DIM);
    float4 v = wrow[sub];
    float* hrow = hacc + (size_t)dst * H_DIM + sub * 4;
    atomicAdd(hrow + 0, v.x * w);
    atomicAdd(hrow + 1, v.y * w);
    atomicAdd(hrow + 2, v.z * w);
    atomicAdd(hrow + 3, v.w * w);
}

// ---------------- h = relu(h + root1 + b1) ----------------
__global__ void h_finalize(float* __restrict__ h,
                           const float* __restrict__ root1,
                           const float* __restrict__ b1) {
    int i = blockIdx.x * blockDim.x + threadIdx.x;   // over N*H/4
    if (i >= N_NODES * H_DIM / 4) return;
    float4 v = ((float4*)h)[i];
    float4 r = ((const float4*)root1)[i];
    float4 b = ((const float4*)b1)[i & (H_DIM / 4 - 1)];
    v.x = fmaxf(v.x + r.x + b.x, 0.0f);
    v.y = fmaxf(v.y + r.y + b.y, 0.0f);
    v.z = fmaxf(v.z + r.z + b.z, 0.0f);
    v.w = fmaxf(v.w + r.w + b.w, 0.0f);
    ((float4*)h)[i] = v;
}

// ---------------- conv2 per-edge matvec: out[dst] += (h[src] @ W2[rel]) / cnt --
// block = 256 threads = 4 waves; each wave (64 lanes) does one edge, lane = c
__global__ void conv2_edge(const int* __restrict__ ei,
                           const int* __restrict__ et,
                           const float* __restrict__ h,
                           const float* __restrict__ W2,
                           const float* __restrict__ cnt,
                           float* __restrict__ out) {
    int lane = threadIdx.x & 63;
    int wv   = threadIdx.x >> 6;    // 0..3
    long e = (long)blockIdx.x * 4 + wv;
    if (e >= N_EDGES) return;
    int src = ei[e];
    int dst = ei[N_EDGES + e];
    int r   = et[e];
    float invc = 1.0f / cnt[dst * N_REL + r];
    const float* hs = h + (size_t)src * H_DIM;
    const float* w2 = W2 + (size_t)r * H_DIM * C_DIM + lane;
    float acc = 0.0f;
    #pragma unroll 8
    for (int k = 0; k < H_DIM; k += 4) {
        float4 hv = *(const float4*)(hs + k);   // broadcast across the wave
        acc += hv.x * w2[(k + 0) * C_DIM];
        acc += hv.y * w2[(k + 1) * C_DIM];
        acc += hv.z * w2[(k + 2) * C_DIM];
        acc += hv.w * w2[(k + 3) * C_DIM];
    }
    atomicAdd(&out[(size_t)dst * C_DIM + lane], acc * invc);
}

// ---------------- out[n] += h[n] @ root2 + b2 ----------------
// one block (64 threads) per node; thread = c
__global__ void root2_kernel(const float* __restrict__ h,
                             const float* __restrict__ root2,
                             const float* __restrict__ b2,
                             float* __restrict__ out) {
    int c = threadIdx.x;
    int n = blockIdx.x;
    const float* hn = h + (size_t)n * H_DIM;
    float acc = b2[c];
    #pragma unroll 8
    for (int k = 0; k < H_DIM; k += 4) {
        float4 hv = *(const float4*)(hn + k);
        acc += hv.x * root2[(k + 0) * C_DIM + c];
        acc += hv.y * root2[(k + 1) * C_DIM + c];
        acc += hv.z * root2[(k + 2) * C_DIM + c];
        acc += hv.w * root2[(k + 3) * C_DIM + c];
    }
    out[(size_t)n * C_DIM + c] += acc;
}

extern "C" void kernel_launch(void* const* d_in, const int* in_sizes, int n_in,
                              void* d_out, int out_size, void* d_ws, size_t ws_size,
                              hipStream_t stream) {
    const int*   ei    = (const int*)d_in[0];    // (2, E): [0..E) = src, [E..2E) = dst
    const int*   et    = (const int*)d_in[1];    // (E,)
    const float* W1    = (const float*)d_in[2];  // (R, N, H)
    const float* root1 = (const float*)d_in[3];  // (N, H)
    const float* b1    = (const float*)d_in[4];  // (H,)
    const float* W2    = (const float*)d_in[5];  // (R, H, C)
    const float* root2 = (const float*)d_in[6];  // (H, C)
    const float* b2    = (const float*)d_in[7];  // (C,)
    float* out = (float*)d_out;                  // (N, C)

    float* cnt = (float*)d_ws;                   // N*R floats
    float* h   = cnt + (size_t)N_NODES * N_REL;  // N*H floats

    // zero accumulators (ws and out are poisoned 0xAA before every call)
    hipMemsetAsync(cnt, 0, ((size_t)N_NODES * N_REL + (size_t)N_NODES * H_DIM) * sizeof(float), stream);
    hipMemsetAsync(out, 0, (size_t)N_NODES * C_DIM * sizeof(float), stream);

    count_kernel<<<(N_EDGES + 255) / 256, 256, 0, stream>>>(ei, et, cnt);
    conv1_scatter<<<N_EDGES / 8, 256, 0, stream>>>(ei, et, W1, cnt, h);
    h_finalize<<<(N_NODES * H_DIM / 4 + 255) / 256, 256, 0, stream>>>(h, root1, b1);
    conv2_edge<<<N_EDGES / 4, 256, 0, stream>>>(ei, et, h, W2, cnt, out);
    root2_kernel<<<N_NODES, 64, 0, stream>>>(h, root2, b2, out);
}

// Round 2
// 791.754 us; speedup vs baseline: 3.2515x; 3.2515x over previous
//
#include <hip/hip_runtime.h>

#define N_NODES 40000
#define N_EDGES 640000
#define N_REL   8
#define H_DIM   128
#define C_DIM   64
#define NR      (N_NODES * N_REL)        // 320000 segments
#define SCAN_NB ((NR + 1023) / 1024)     // 313 scan blocks

// ---------------- counts: cnt[dst*R + rel] += 1 (int) ----------------
__global__ void count_kernel(const int* __restrict__ ei,
                             const int* __restrict__ et,
                             int* __restrict__ cnt) {
    int e = blockIdx.x * blockDim.x + threadIdx.x;
    if (e < N_EDGES) {
        int dst = ei[N_EDGES + e];
        atomicAdd(&cnt[dst * N_REL + et[e]], 1);
    }
}

// ---------------- exclusive scan over NR, 1024 elems per block ----------------
__global__ void scanA(const int* __restrict__ cnt, int* __restrict__ start,
                      int* __restrict__ bsum) {
    __shared__ int lds[256];
    int base = blockIdx.x * 1024;
    int t = threadIdx.x;
    int v[4]; int s = 0;
    #pragma unroll
    for (int j = 0; j < 4; j++) {
        int idx = base + t * 4 + j;
        v[j] = (idx < NR) ? cnt[idx] : 0;
        s += v[j];
    }
    lds[t] = s; __syncthreads();
    int x = s;
    #pragma unroll
    for (int off = 1; off < 256; off <<= 1) {
        int y = (t >= off) ? lds[t - off] : 0;
        __syncthreads();
        x += y;
        lds[t] = x;
        __syncthreads();
    }
    int excl = x - s;                  // exclusive prefix of this thread's chunk
    #pragma unroll
    for (int j = 0; j < 4; j++) {
        int idx = base + t * 4 + j;
        if (idx < NR) start[idx] = excl;
        excl += v[j];
    }
    if (t == 255) bsum[blockIdx.x] = x;
}

__global__ void scanB(int* __restrict__ bsum, int* __restrict__ start) {
    if (threadIdx.x == 0 && blockIdx.x == 0) {
        int run = 0;
        for (int i = 0; i < SCAN_NB; i++) { int v = bsum[i]; bsum[i] = run; run += v; }
        start[NR] = run;               // == N_EDGES
    }
}

__global__ void scanC(int* __restrict__ start, const int* __restrict__ bsum) {
    int idx = blockIdx.x * blockDim.x + threadIdx.x;
    if (idx < NR) start[idx] += bsum[idx >> 10];
}

// ---------------- reorder: ssrc grouped by segment ----------------
__global__ void reorder_kernel(const int* __restrict__ ei, const int* __restrict__ et,
                               const int* __restrict__ start, int* __restrict__ cursor,
                               int* __restrict__ ssrc) {
    int e = blockIdx.x * blockDim.x + threadIdx.x;
    if (e < N_EDGES) {
        int seg = ei[N_EDGES + e] * N_REL + et[e];
        int pos = atomicAdd(&cursor[seg], 1);
        ssrc[start[seg] + pos] = ei[e];
    }
}

// ---------------- conv1: one wave per node, no atomics ----------------
// h[n] = relu( sum_r mean_{seg(n,r)} W1[r,src,:] + root1[n] + b1 )
__global__ void conv1_node(const int* __restrict__ ssrc, const int* __restrict__ start,
                           const float* __restrict__ W1, const float* __restrict__ root1,
                           const float* __restrict__ b1, float* __restrict__ h) {
    int lane = threadIdx.x & 63;
    int n = blockIdx.x * (blockDim.x >> 6) + (threadIdx.x >> 6);
    if (n >= N_NODES) return;
    float2 acc = {0.f, 0.f};
    for (int r = 0; r < N_REL; r++) {
        int s0 = start[n * N_REL + r], s1 = start[n * N_REL + r + 1];
        if (s1 == s0) continue;
        float inv = 1.0f / (float)(s1 - s0);
        float2 rs = {0.f, 0.f};
        for (int e = s0; e < s1; e++) {
            const float2* row = (const float2*)(W1 + ((size_t)r * N_NODES + ssrc[e]) * H_DIM);
            float2 v = row[lane];
            rs.x += v.x; rs.y += v.y;
        }
        acc.x += rs.x * inv; acc.y += rs.y * inv;
    }
    float2 rt = ((const float2*)root1)[(size_t)n * 64 + lane];
    float2 bb = ((const float2*)b1)[lane];
    float2 o;
    o.x = fmaxf(acc.x + rt.x + bb.x, 0.f);
    o.y = fmaxf(acc.y + rt.y + bb.y, 0.f);
    ((float2*)h)[(size_t)n * 64 + lane] = o;
}

// ---------------- conv2: 64 nodes per block, W2[r] staged in LDS ----------------
// out[n,c] = sum_r (mean_{seg(n,r)} h[src]) @ W2[r] + h[n] @ root2 + b2
__global__ void conv2_node(const int* __restrict__ ssrc, const int* __restrict__ start,
                           const float* __restrict__ h, const float* __restrict__ W2,
                           const float* __restrict__ root2, const float* __restrict__ b2,
                           float* __restrict__ out) {
    __shared__ float wlds[H_DIM * C_DIM];   // [k][c] layout: bank = c%32 -> 2-way (free)
    __shared__ float hslds[4][H_DIM];       // per-wave mean_h scratch (broadcast reads)
    int lane = threadIdx.x & 63;
    int wv   = threadIdx.x >> 6;
    int nbase = blockIdx.x * 64 + wv * 16;
    float acc[16];
    #pragma unroll
    for (int i = 0; i < 16; i++) acc[i] = 0.f;

    for (int rr = 0; rr < N_REL + 1; rr++) {
        const float4* wsrc = (const float4*)((rr < N_REL) ? (W2 + (size_t)rr * H_DIM * C_DIM)
                                                          : root2);
        __syncthreads();   // all waves done reading previous wlds
        for (int i = threadIdx.x; i < H_DIM * C_DIM / 4; i += 256)
            ((float4*)wlds)[i] = wsrc[i];
        __syncthreads();

        for (int i = 0; i < 16; i++) {
            int n = nbase + i;
            float2 hs = {0.f, 0.f};
            float inv;
            if (rr < N_REL) {
                int s0 = start[n * N_REL + rr], s1 = start[n * N_REL + rr + 1];
                if (s0 == s1) continue;
                inv = 1.0f / (float)(s1 - s0);
                for (int e = s0; e < s1; e++) {
                    const float2* row = (const float2*)(h + (size_t)ssrc[e] * H_DIM);
                    float2 v = row[lane];
                    hs.x += v.x; hs.y += v.y;
                }
            } else {
                hs = ((const float2*)(h + (size_t)n * H_DIM))[lane];
                inv = 1.f;
            }
            hslds[wv][lane * 2]     = hs.x * inv;
            hslds[wv][lane * 2 + 1] = hs.y * inv;
            // wave-synchronous: compiler inserts lgkmcnt wait before dependent reads
            float d = 0.f;
            #pragma unroll
            for (int k = 0; k < H_DIM; k += 4) {
                float4 hv = *(const float4*)&hslds[wv][k];
                d += hv.x * wlds[(k + 0) * C_DIM + lane];
                d += hv.y * wlds[(k + 1) * C_DIM + lane];
                d += hv.z * wlds[(k + 2) * C_DIM + lane];
                d += hv.w * wlds[(k + 3) * C_DIM + lane];
            }
            acc[i] += d;
        }
    }
    #pragma unroll
    for (int i = 0; i < 16; i++)
        out[(size_t)(nbase + i) * C_DIM + lane] = acc[i] + b2[lane];
}

extern "C" void kernel_launch(void* const* d_in, const int* in_sizes, int n_in,
                              void* d_out, int out_size, void* d_ws, size_t ws_size,
                              hipStream_t stream) {
    const int*   ei    = (const int*)d_in[0];
    const int*   et    = (const int*)d_in[1];
    const float* W1    = (const float*)d_in[2];
    const float* root1 = (const float*)d_in[3];
    const float* b1    = (const float*)d_in[4];
    const float* W2    = (const float*)d_in[5];
    const float* root2 = (const float*)d_in[6];
    const float* b2    = (const float*)d_in[7];
    float* out = (float*)d_out;

    // ws layout (all offsets 16B-aligned)
    int*   cnt    = (int*)d_ws;              // NR
    int*   start  = cnt + NR;                // NR + 16 (start[NR] used)
    int*   bsum   = start + NR + 16;         // 512
    int*   cursor = bsum + 512;              // NR
    int*   ssrc   = cursor + NR;             // E
    float* h      = (float*)(ssrc + N_EDGES);// N*H

    hipMemsetAsync(cnt,    0, (size_t)NR * sizeof(int), stream);
    hipMemsetAsync(cursor, 0, (size_t)NR * sizeof(int), stream);

    count_kernel  <<<(N_EDGES + 255) / 256, 256, 0, stream>>>(ei, et, cnt);
    scanA         <<<SCAN_NB, 256, 0, stream>>>(cnt, start, bsum);
    scanB         <<<1, 64, 0, stream>>>(bsum, start);
    scanC         <<<(NR + 255) / 256, 256, 0, stream>>>(start, bsum);
    reorder_kernel<<<(N_EDGES + 255) / 256, 256, 0, stream>>>(ei, et, start, cursor, ssrc);
    conv1_node    <<<N_NODES / 4, 256, 0, stream>>>(ssrc, start, W1, root1, b1, h);
    conv2_node    <<<N_NODES / 64, 256, 0, stream>>>(ssrc, start, h, W2, root2, b2, out);
}

// Round 3
// 554.742 us; speedup vs baseline: 4.6407x; 1.4272x over previous
//
#include <hip/hip_runtime.h>

#define N_NODES 40000
#define N_EDGES 640000
#define N_REL   8
#define H_DIM   128
#define C_DIM   64
#define NR      (N_NODES * N_REL)        // 320000 segments
#define SCAN_NB ((NR + 1023) / 1024)     // 313 scan blocks

typedef __attribute__((ext_vector_type(8))) short bf16x8;
typedef __attribute__((ext_vector_type(4))) float f32x4;

__device__ inline uint rne_bf16(float x) {
    uint u = __float_as_uint(x);
    return (u + 0x7FFFu + ((u >> 16) & 1u)) >> 16;
}
__device__ inline uint pack_bf16(float x, float y) {   // x -> low half (even col)
    return rne_bf16(x) | (rne_bf16(y) << 16);
}

// ---------------- counts ----------------
__global__ void count_kernel(const int* __restrict__ ei,
                             const int* __restrict__ et,
                             int* __restrict__ cnt) {
    int e = blockIdx.x * blockDim.x + threadIdx.x;
    if (e < N_EDGES) {
        int dst = ei[N_EDGES + e];
        atomicAdd(&cnt[dst * N_REL + et[e]], 1);
    }
}

// ---------------- exclusive scan over NR ----------------
__global__ void scanA(const int* __restrict__ cnt, int* __restrict__ start,
                      int* __restrict__ bsum) {
    __shared__ int lds[256];
    int base = blockIdx.x * 1024;
    int t = threadIdx.x;
    int v[4]; int s = 0;
    #pragma unroll
    for (int j = 0; j < 4; j++) {
        int idx = base + t * 4 + j;
        v[j] = (idx < NR) ? cnt[idx] : 0;
        s += v[j];
    }
    lds[t] = s; __syncthreads();
    int x = s;
    #pragma unroll
    for (int off = 1; off < 256; off <<= 1) {
        int y = (t >= off) ? lds[t - off] : 0;
        __syncthreads();
        x += y;
        lds[t] = x;
        __syncthreads();
    }
    int excl = x - s;
    #pragma unroll
    for (int j = 0; j < 4; j++) {
        int idx = base + t * 4 + j;
        if (idx < NR) start[idx] = excl;
        excl += v[j];
    }
    if (t == 255) bsum[blockIdx.x] = x;
}

__global__ void scanB(int* __restrict__ bsum, int* __restrict__ start) {
    if (threadIdx.x == 0 && blockIdx.x == 0) {
        int run = 0;
        for (int i = 0; i < SCAN_NB; i++) { int v = bsum[i]; bsum[i] = run; run += v; }
        start[NR] = run;               // == N_EDGES
    }
}

__global__ void scanC(int* __restrict__ start, const int* __restrict__ bsum) {
    int idx = blockIdx.x * blockDim.x + threadIdx.x;
    if (idx < NR) start[idx] += bsum[idx >> 10];
}

// ---------------- reorder: spack = src | (r<<16), swgt = 1/cnt[seg] ----------------
__global__ void reorder_kernel(const int* __restrict__ ei, const int* __restrict__ et,
                               const int* __restrict__ start, const int* __restrict__ cnt,
                               int* __restrict__ cursor,
                               int* __restrict__ spack, float* __restrict__ swgt) {
    int e = blockIdx.x * blockDim.x + threadIdx.x;
    if (e < N_EDGES) {
        int r = et[e];
        int seg = ei[N_EDGES + e] * N_REL + r;
        int pos = atomicAdd(&cursor[seg], 1);
        int o = start[seg] + pos;
        spack[o] = ei[e] | (r << 16);          // src < 65536
        swgt[o]  = 1.0f / (float)cnt[seg];
    }
}

// ---------------- w2t: pre-swizzled bf16 [9][c=64][k=128] (r=8 is root2) --------
__global__ void convert_w2(const float* __restrict__ W2, const float* __restrict__ root2,
                           ushort* __restrict__ w2t) {
    int i = blockIdx.x * 256 + threadIdx.x;    // 9*64*128 = 73728
    if (i >= 9 * C_DIM * H_DIM) return;
    int k = i & 127; int c = (i >> 7) & 63; int r = i >> 13;
    float v = (r < 8) ? W2[((size_t)r * H_DIM + k) * C_DIM + c]
                      : root2[(size_t)k * C_DIM + c];
    int byte = (c * 256 + k * 2) ^ ((c & 7) << 4);   // XOR-swizzle (T2)
    w2t[(size_t)r * 8192 + (byte >> 1)] = (ushort)rne_bf16(v);
}

// ---------------- conv1: flat edge loop per node; writes h as packed bf16 -------
// h[n] = relu( sum_e w_e * W1[r_e, src_e, :] + root1[n] + b1 )
__global__ void conv1_flat(const int* __restrict__ spack, const float* __restrict__ swgt,
                           const int* __restrict__ start,
                           const float* __restrict__ W1, const float* __restrict__ root1,
                           const float* __restrict__ b1, uint* __restrict__ h16) {
    int lane = threadIdx.x & 63;
    int n = blockIdx.x * 4 + (threadIdx.x >> 6);
    int e0 = start[n * N_REL], e1 = start[n * N_REL + N_REL];
    float ax = 0.f, ay = 0.f;
    for (int e = e0; e < e1; e++) {
        int p = spack[e]; float w = swgt[e];
        int src = p & 0xFFFF; int r = p >> 16;
        const float2* row = (const float2*)(W1 + ((size_t)r * N_NODES + src) * H_DIM);
        float2 v = row[lane];
        ax += w * v.x; ay += w * v.y;
    }
    float2 rt = ((const float2*)root1)[(size_t)n * 64 + lane];
    float2 bb = ((const float2*)b1)[lane];
    ax = fmaxf(ax + rt.x + bb.x, 0.f);
    ay = fmaxf(ay + rt.y + bb.y, 0.f);
    h16[(size_t)n * 64 + lane] = pack_bf16(ax, ay);
}

// ---------------- conv2: 32 nodes/block, 8 waves, MFMA 16x16x32 bf16 -----------
// out[n,c] = sum_{r<8} mean_{seg(n,r)} h[src] @ W2[r] + h[n] @ root2 + b2
__global__ __launch_bounds__(512) void
conv2_fused(const int* __restrict__ spack, const int* __restrict__ start,
            const uint* __restrict__ h16, const ushort* __restrict__ w2t,
            const float* __restrict__ b2, float* __restrict__ out) {
    __shared__ uint ldsA[32 * 64];   // 32 rows x 256B (bf16, swizzled) = 8 KB
    __shared__ uint ldsB[4096];      // 64 cols x 256B (bf16, pre-swizzled) = 16 KB
    int lane = threadIdx.x & 63;
    int wv   = threadIdx.x >> 6;
    int nbase = blockIdx.x * 32;
    int rtile = wv >> 2, ctile = wv & 3;     // wave's 16x16 out-tile
    f32x4 acc = {0.f, 0.f, 0.f, 0.f};

    const char* pA = (const char*)ldsA;
    const char* pB = (const char*)ldsB;
    int arow = rtile * 16 + (lane & 15);
    int bcol = ctile * 16 + (lane & 15);
    int qk   = (lane >> 4) * 16;             // byte offset of this lane's 8 bf16 in k

    for (int rr = 0; rr < 9; rr++) {
        // stage W2T[rr] (pre-swizzled, linear copy)
        const uint4* bsrc = (const uint4*)(w2t + (size_t)rr * 8192);
        ((uint4*)ldsB)[threadIdx.x]       = bsrc[threadIdx.x];
        ((uint4*)ldsB)[threadIdx.x + 512] = bsrc[threadIdx.x + 512];
        // gather mean-h rows for this wave's 4 nodes
        for (int i = 0; i < 4; i++) {
            int irow = wv * 4 + i;
            int n = nbase + irow;
            int byte = (irow * 256 + lane * 4) ^ ((irow & 7) << 4);
            if (rr < 8) {
                int seg = n * N_REL + rr;
                int s0 = start[seg], s1 = start[seg + 1];
                float ax = 0.f, ay = 0.f;
                for (int e = s0; e < s1; e++) {
                    int src = spack[e] & 0xFFFF;
                    uint hv = h16[(size_t)src * 64 + lane];
                    ax += __uint_as_float(hv << 16);
                    ay += __uint_as_float(hv & 0xFFFF0000u);
                }
                if (s1 > s0) { float inv = 1.f / (float)(s1 - s0); ax *= inv; ay *= inv; }
                ldsA[byte >> 2] = pack_bf16(ax, ay);
            } else {
                ldsA[byte >> 2] = h16[(size_t)n * 64 + lane];   // root2 slab: row = h[n]
            }
        }
        __syncthreads();
        #pragma unroll
        for (int kf = 0; kf < 4; kf++) {
            int abyte = (arow * 256 + kf * 64 + qk) ^ ((arow & 7) << 4);
            int bbyte = (bcol * 256 + kf * 64 + qk) ^ ((bcol & 7) << 4);
            bf16x8 a = *(const bf16x8*)(pA + abyte);
            bf16x8 b = *(const bf16x8*)(pB + bbyte);
            acc = __builtin_amdgcn_mfma_f32_16x16x32_bf16(a, b, acc, 0, 0, 0);
        }
        __syncthreads();
    }
    // epilogue: C/D layout col = lane&15, row = (lane>>4)*4 + j  [m89-verified]
    int ocol = ctile * 16 + (lane & 15);
    float bv = b2[ocol];
    #pragma unroll
    for (int j = 0; j < 4; j++) {
        int orow = nbase + rtile * 16 + (lane >> 4) * 4 + j;
        out[(size_t)orow * C_DIM + ocol] = acc[j] + bv;
    }
}

extern "C" void kernel_launch(void* const* d_in, const int* in_sizes, int n_in,
                              void* d_out, int out_size, void* d_ws, size_t ws_size,
                              hipStream_t stream) {
    const int*   ei    = (const int*)d_in[0];
    const int*   et    = (const int*)d_in[1];
    const float* W1    = (const float*)d_in[2];
    const float* root1 = (const float*)d_in[3];
    const float* b1    = (const float*)d_in[4];
    const float* W2    = (const float*)d_in[5];
    const float* root2 = (const float*)d_in[6];
    const float* b2    = (const float*)d_in[7];
    float* out = (float*)d_out;

    // ws layout (ints unless noted)
    int*    cnt    = (int*)d_ws;                 // NR
    int*    start  = cnt + NR;                   // NR + 16
    int*    bsum   = start + NR + 16;            // 512
    int*    cursor = bsum + 512;                 // NR
    int*    spack  = cursor + NR;                // E
    float*  swgt   = (float*)(spack + N_EDGES);  // E
    uint*   h16    = (uint*)(swgt + N_EDGES);    // N*64  (packed bf16 h)
    ushort* w2t    = (ushort*)(h16 + (size_t)N_NODES * 64);  // 9*8192

    hipMemsetAsync(cnt,    0, (size_t)NR * sizeof(int), stream);
    hipMemsetAsync(cursor, 0, (size_t)NR * sizeof(int), stream);

    count_kernel  <<<(N_EDGES + 255) / 256, 256, 0, stream>>>(ei, et, cnt);
    convert_w2    <<<(9 * C_DIM * H_DIM + 255) / 256, 256, 0, stream>>>(W2, root2, w2t);
    scanA         <<<SCAN_NB, 256, 0, stream>>>(cnt, start, bsum);
    scanB         <<<1, 64, 0, stream>>>(bsum, start);
    scanC         <<<(NR + 255) / 256, 256, 0, stream>>>(start, bsum);
    reorder_kernel<<<(N_EDGES + 255) / 256, 256, 0, stream>>>(ei, et, start, cnt, cursor, spack, swgt);
    conv1_flat    <<<N_NODES / 4, 256, 0, stream>>>(spack, swgt, start, W1, root1, b1, h16);
    conv2_fused   <<<N_NODES / 32, 512, 0, stream>>>(spack, start, h16, w2t, b2, out);
}

// Round 4
// 482.732 us; speedup vs baseline: 5.3329x; 1.1492x over previous
//
#include <hip/hip_runtime.h>

#define N_NODES 40000
#define N_EDGES 640000
#define N_REL   8
#define H_DIM   128
#define C_DIM   64
#define NR      (N_NODES * N_REL)
#define SCAN_NB ((N_NODES + 1023) / 1024)   // 40 blocks over node degrees

typedef __attribute__((ext_vector_type(8))) short bf16x8;
typedef __attribute__((ext_vector_type(4))) float f32x4;

__device__ inline uint rne_bf16(float x) {
    uint u = __float_as_uint(x);
    return (u + 0x7FFFu + ((u >> 16) & 1u)) >> 16;
}
__device__ inline uint pack_bf16(float x, float y) {   // x -> low half (even col)
    return rne_bf16(x) | (rne_bf16(y) << 16);
}

// ---------------- counts: per-(dst,rel) for weights, per-dst for CSR ----------
__global__ void count_kernel(const int* __restrict__ ei,
                             const int* __restrict__ et,
                             int* __restrict__ cnt, int* __restrict__ deg) {
    int e = blockIdx.x * blockDim.x + threadIdx.x;
    if (e < N_EDGES) {
        int dst = ei[N_EDGES + e];
        atomicAdd(&cnt[dst * N_REL + et[e]], 1);
        atomicAdd(&deg[dst], 1);
    }
}

// ---------------- exclusive scan over node degrees (N_NODES) -------------------
__global__ void scanA(const int* __restrict__ deg, int* __restrict__ start,
                      int* __restrict__ bsum) {
    __shared__ int lds[256];
    int base = blockIdx.x * 1024;
    int t = threadIdx.x;
    int v[4]; int s = 0;
    #pragma unroll
    for (int j = 0; j < 4; j++) {
        int idx = base + t * 4 + j;
        v[j] = (idx < N_NODES) ? deg[idx] : 0;
        s += v[j];
    }
    lds[t] = s; __syncthreads();
    int x = s;
    #pragma unroll
    for (int off = 1; off < 256; off <<= 1) {
        int y = (t >= off) ? lds[t - off] : 0;
        __syncthreads();
        x += y;
        lds[t] = x;
        __syncthreads();
    }
    int excl = x - s;
    #pragma unroll
    for (int j = 0; j < 4; j++) {
        int idx = base + t * 4 + j;
        if (idx < N_NODES) start[idx] = excl;
        excl += v[j];
    }
    if (t == 255) bsum[blockIdx.x] = x;
}

__global__ void scanB(int* __restrict__ bsum, int* __restrict__ start) {
    if (threadIdx.x == 0 && blockIdx.x == 0) {
        int run = 0;
        for (int i = 0; i < SCAN_NB; i++) { int v = bsum[i]; bsum[i] = run; run += v; }
        start[N_NODES] = run;          // == N_EDGES
    }
}

__global__ void scanC(int* __restrict__ start, const int* __restrict__ bsum) {
    int idx = blockIdx.x * blockDim.x + threadIdx.x;
    if (idx < N_NODES) start[idx] += bsum[idx >> 10];
}

// ---------------- reorder: per-node edge lists, spack = src|(r<<16) ------------
__global__ void reorder_kernel(const int* __restrict__ ei, const int* __restrict__ et,
                               const int* __restrict__ start, const int* __restrict__ cnt,
                               int* __restrict__ cursor,
                               int* __restrict__ spack, float* __restrict__ swgt) {
    int e = blockIdx.x * blockDim.x + threadIdx.x;
    if (e < N_EDGES) {
        int r = et[e];
        int dst = ei[N_EDGES + e];
        int pos = atomicAdd(&cursor[dst], 1);
        int o = start[dst] + pos;
        spack[o] = ei[e] | (r << 16);          // src < 65536
        swgt[o]  = 1.0f / (float)cnt[dst * N_REL + r];
    }
}

// ---------------- w2t: pre-swizzled bf16 [9][c=64][k=128] (r=8 is root2) -------
__global__ void convert_w2(const float* __restrict__ W2, const float* __restrict__ root2,
                           ushort* __restrict__ w2t) {
    int i = blockIdx.x * 256 + threadIdx.x;    // 9*64*128 = 73728
    if (i >= 9 * C_DIM * H_DIM) return;
    int k = i & 127; int c = (i >> 7) & 63; int r = i >> 13;
    float v = (r < 8) ? W2[((size_t)r * H_DIM + k) * C_DIM + c]
                      : root2[(size_t)k * C_DIM + c];
    int byte = (c * 256 + k * 2) ^ ((c & 7) << 4);   // XOR-swizzle (T2)
    w2t[(size_t)r * 8192 + (byte >> 1)] = (ushort)rne_bf16(v);
}

// ---------------- conv1: 1 node/block, 4 waves split edges, LDS reduce ---------
// h[n] = relu( sum_e w_e * W1[r_e, src_e, :] + root1[n] + b1 )
__global__ __launch_bounds__(256) void
conv1_node4(const int* __restrict__ spack, const float* __restrict__ swgt,
            const int* __restrict__ start,
            const float* __restrict__ W1, const float* __restrict__ root1,
            const float* __restrict__ b1, uint* __restrict__ h16) {
    __shared__ float2 red[4][64];
    int t = threadIdx.x;
    int lane = t & 63, wv = t >> 6;
    int n = blockIdx.x;
    int e0 = start[n], e1 = start[n + 1];
    float ax = 0.f, ay = 0.f;
    for (int e = e0 + wv; e < e1; e += 4) {
        int p = spack[e]; float w = swgt[e];
        const float2* row = (const float2*)(W1 + ((size_t)(p >> 16) * N_NODES + (p & 0xFFFF)) * H_DIM);
        float2 v = row[lane];
        ax += w * v.x; ay += w * v.y;
    }
    red[wv][lane] = make_float2(ax, ay);
    __syncthreads();
    if (t < 64) {
        float2 s0 = red[0][t], s1 = red[1][t], s2 = red[2][t], s3 = red[3][t];
        float sx = s0.x + s1.x + s2.x + s3.x;
        float sy = s0.y + s1.y + s2.y + s3.y;
        float2 rt = ((const float2*)root1)[(size_t)n * 64 + t];
        float2 bb = ((const float2*)b1)[t];
        sx = fmaxf(sx + rt.x + bb.x, 0.f);
        sy = fmaxf(sy + rt.y + bb.y, 0.f);
        h16[(size_t)n * 64 + t] = pack_bf16(sx, sy);
    }
}

// ---------------- zgemm: Z[r] = h @ W2[r] (bf16), out = h @ root2 + b2 ---------
// 64 nodes/block, 4 waves; A-tile staged once, 9 B-slabs
__global__ __launch_bounds__(256) void
zgemm(const uint* __restrict__ h16, const ushort* __restrict__ w2t,
      const float* __restrict__ b2, ushort* __restrict__ zb, float* __restrict__ out) {
    __shared__ uint ldsA[4096];   // 64 rows x 256B swizzled
    __shared__ uint ldsB[4096];
    int t = threadIdx.x, lane = t & 63, wv = t >> 6;
    int nbase = blockIdx.x * 64;
    for (int i = t; i < 4096; i += 256) {
        int row = i >> 6, cu = i & 63;
        int byte = (row * 256 + cu * 4) ^ ((row & 7) << 4);
        ldsA[byte >> 2] = h16[(size_t)(nbase + row) * 64 + cu];
    }
    const char* pA = (const char*)ldsA;
    const char* pB = (const char*)ldsB;
    int arow = wv * 16 + (lane & 15);
    int qk = (lane >> 4) * 16;
    for (int rr = 0; rr < 9; rr++) {
        __syncthreads();   // also covers initial A staging; protects ldsB reuse
        const uint4* bsrc = (const uint4*)(w2t + (size_t)rr * 8192);
        ((uint4*)ldsB)[t]       = bsrc[t];
        ((uint4*)ldsB)[t + 256] = bsrc[t + 256];
        ((uint4*)ldsB)[t + 512] = bsrc[t + 512];
        ((uint4*)ldsB)[t + 768] = bsrc[t + 768];
        __syncthreads();
        f32x4 acc[4];
        #pragma unroll
        for (int ct = 0; ct < 4; ct++) acc[ct] = (f32x4){0.f, 0.f, 0.f, 0.f};
        #pragma unroll
        for (int ct = 0; ct < 4; ct++) {
            int bcol = ct * 16 + (lane & 15);
            #pragma unroll
            for (int kf = 0; kf < 4; kf++) {
                int abyte = (arow * 256 + kf * 64 + qk) ^ ((arow & 7) << 4);
                int bbyte = (bcol * 256 + kf * 64 + qk) ^ ((bcol & 7) << 4);
                bf16x8 a = *(const bf16x8*)(pA + abyte);
                bf16x8 b = *(const bf16x8*)(pB + bbyte);
                acc[ct] = __builtin_amdgcn_mfma_f32_16x16x32_bf16(a, b, acc[ct], 0, 0, 0);
            }
        }
        // C/D layout: col = lane&15 (+16*ct), row = (lane>>4)*4 + j
        #pragma unroll
        for (int ct = 0; ct < 4; ct++) {
            int c = ct * 16 + (lane & 15);
            #pragma unroll
            for (int j = 0; j < 4; j++) {
                int n = nbase + wv * 16 + (lane >> 4) * 4 + j;
                if (rr < 8)
                    zb[((size_t)rr * N_NODES + n) * 64 + c] = (ushort)rne_bf16(acc[ct][j]);
                else
                    out[(size_t)n * 64 + c] = acc[ct][j] + b2[c];
            }
        }
    }
}

// ---------------- zgather: out[n] += sum_e w_e * Z[r_e, src_e, :] --------------
// 4 nodes/block, 1 wave/node, 2 edges in flight (32 lanes each)
__global__ __launch_bounds__(256) void
zgather(const int* __restrict__ spack, const float* __restrict__ swgt,
        const int* __restrict__ start, const uint* __restrict__ zb32,
        float* __restrict__ out) {
    int lane = threadIdx.x & 63, wv = threadIdx.x >> 6;
    int n = blockIdx.x * 4 + wv;
    int eg = lane >> 5, c2 = lane & 31;    // edge-group, uint col (2 bf16)
    int e0 = start[n], e1 = start[n + 1];
    float ax = 0.f, ay = 0.f;
    for (int e = e0 + eg; e < e1; e += 2) {
        int p = spack[e]; float w = swgt[e];
        uint zv = zb32[((size_t)(p >> 16) * N_NODES + (p & 0xFFFF)) * 32 + c2];
        ax += w * __uint_as_float(zv << 16);
        ay += w * __uint_as_float(zv & 0xFFFF0000u);
    }
    ax += __shfl_xor(ax, 32);
    ay += __shfl_xor(ay, 32);
    if (eg == 0) {
        float2* o = (float2*)out + (size_t)n * 32 + c2;
        float2 v = *o;
        v.x += ax; v.y += ay;
        *o = v;
    }
}

extern "C" void kernel_launch(void* const* d_in, const int* in_sizes, int n_in,
                              void* d_out, int out_size, void* d_ws, size_t ws_size,
                              hipStream_t stream) {
    const int*   ei    = (const int*)d_in[0];
    const int*   et    = (const int*)d_in[1];
    const float* W1    = (const float*)d_in[2];
    const float* root1 = (const float*)d_in[3];
    const float* b1    = (const float*)d_in[4];
    const float* W2    = (const float*)d_in[5];
    const float* root2 = (const float*)d_in[6];
    const float* b2    = (const float*)d_in[7];
    float* out = (float*)d_out;

    // ws layout: [cnt NR][deg N][cursor N] (zeroed together), then the rest
    int*    cnt    = (int*)d_ws;                    // NR
    int*    deg    = cnt + NR;                      // N
    int*    cursor = deg + N_NODES;                 // N
    int*    start  = cursor + N_NODES;              // N+16
    int*    bsum   = start + N_NODES + 16;          // 512
    int*    spack  = bsum + 512;                    // E
    float*  swgt   = (float*)(spack + N_EDGES);     // E
    uint*   h16    = (uint*)(swgt + N_EDGES);       // N*64
    ushort* w2t    = (ushort*)(h16 + (size_t)N_NODES * 64);   // 9*8192
    ushort* zb     = (ushort*)(w2t + 9 * 8192);     // 8*N*64 bf16 = 41 MB

    hipMemsetAsync(cnt, 0, (size_t)(NR + 2 * N_NODES) * sizeof(int), stream);

    count_kernel  <<<(N_EDGES + 255) / 256, 256, 0, stream>>>(ei, et, cnt, deg);
    convert_w2    <<<(9 * C_DIM * H_DIM + 255) / 256, 256, 0, stream>>>(W2, root2, w2t);
    scanA         <<<SCAN_NB, 256, 0, stream>>>(deg, start, bsum);
    scanB         <<<1, 64, 0, stream>>>(bsum, start);
    scanC         <<<(N_NODES + 255) / 256, 256, 0, stream>>>(start, bsum);
    reorder_kernel<<<(N_EDGES + 255) / 256, 256, 0, stream>>>(ei, et, start, cnt, cursor, spack, swgt);
    conv1_node4   <<<N_NODES, 256, 0, stream>>>(spack, swgt, start, W1, root1, b1, h16);
    zgemm         <<<N_NODES / 64, 256, 0, stream>>>(h16, w2t, b2, zb, out);
    zgather       <<<N_NODES / 4, 256, 0, stream>>>(spack, swgt, start, (const uint*)zb, out);
}

// Round 6
// 446.673 us; speedup vs baseline: 5.7634x; 1.0807x over previous
//
#include <hip/hip_runtime.h>

#define N_NODES 40000
#define N_EDGES 640000
#define N_REL   8
#define H_DIM   128
#define C_DIM   64
#define NR      (N_NODES * N_REL)
#define SCAN_ITEMS 40   // 1024 * 40 = 40960 >= N_NODES

typedef __attribute__((ext_vector_type(8))) short bf16x8;
typedef __attribute__((ext_vector_type(4))) float f32x4;

__device__ inline uint rne_bf16(float x) {
    uint u = __float_as_uint(x);
    return (u + 0x7FFFu + ((u >> 16) & 1u)) >> 16;
}
__device__ inline uint pack_bf16(float x, float y) {   // x -> low half
    return rne_bf16(x) | (rne_bf16(y) << 16);
}
__device__ inline float bf_lo(uint v) { return __uint_as_float(v << 16); }
__device__ inline float bf_hi(uint v) { return __uint_as_float(v & 0xFFFF0000u); }

// ---------------- counts: per-(dst,rel) + per-dst degree ----------------
__global__ void count_kernel(const int* __restrict__ ei,
                             const int* __restrict__ et,
                             int* __restrict__ cnt, int* __restrict__ deg) {
    int e = blockIdx.x * blockDim.x + threadIdx.x;
    if (e < N_EDGES) {
        int dst = ei[N_EDGES + e];
        atomicAdd(&cnt[dst * N_REL + et[e]], 1);
        atomicAdd(&deg[dst], 1);
    }
}

// ---------------- single-block exclusive scan over node degrees ----------------
__global__ __launch_bounds__(1024) void
scan_all(const int* __restrict__ deg, int* __restrict__ start) {
    __shared__ int lds[1024];
    int t = threadIdx.x;
    int v[SCAN_ITEMS]; int s = 0;
    #pragma unroll
    for (int j = 0; j < SCAN_ITEMS; j++) {
        int idx = t * SCAN_ITEMS + j;
        v[j] = (idx < N_NODES) ? deg[idx] : 0;
        s += v[j];
    }
    lds[t] = s; __syncthreads();
    int x = s;
    for (int off = 1; off < 1024; off <<= 1) {
        int y = (t >= off) ? lds[t - off] : 0;
        __syncthreads();
        x += y; lds[t] = x;
        __syncthreads();
    }
    int excl = x - s;
    #pragma unroll
    for (int j = 0; j < SCAN_ITEMS; j++) {
        int idx = t * SCAN_ITEMS + j;
        if (idx < N_NODES) start[idx] = excl;
        excl += v[j];
    }
    if (t == 1023) start[N_NODES] = x;   // == N_EDGES
}

// ---------------- reorder: em[o] = (src|r<<16, bits(1/cnt[dst,r])) ----------------
__global__ void reorder_kernel(const int* __restrict__ ei, const int* __restrict__ et,
                               const int* __restrict__ start, const int* __restrict__ cnt,
                               int* __restrict__ cursor, int2* __restrict__ em) {
    int e = blockIdx.x * blockDim.x + threadIdx.x;
    if (e < N_EDGES) {
        int r = et[e];
        int dst = ei[N_EDGES + e];
        int pos = atomicAdd(&cursor[dst], 1);
        em[start[dst] + pos] =
            make_int2(ei[e] | (r << 16),
                      __float_as_int(1.0f / (float)cnt[dst * N_REL + r]));
    }
}

// ---------------- w2t: pre-swizzled bf16 [9][c=64][k=128] (r=8 is root2) -------
__global__ void convert_w2(const float* __restrict__ W2, const float* __restrict__ root2,
                           ushort* __restrict__ w2t) {
    int i = blockIdx.x * 256 + threadIdx.x;    // 9*64*128 = 73728
    if (i >= 9 * C_DIM * H_DIM) return;
    int k = i & 127; int c = (i >> 7) & 63; int r = i >> 13;
    float v = (r < 8) ? W2[((size_t)r * H_DIM + k) * C_DIM + c]
                      : root2[(size_t)k * C_DIM + c];
    int byte = (c * 256 + k * 2) ^ ((c & 7) << 4);   // XOR-swizzle (T2)
    w2t[(size_t)r * 8192 + (byte >> 1)] = (ushort)rne_bf16(v);
}

// ---------------- conv1: 1 wave/node, metadata broadcast, 4 rows in flight -----
// NOTE: all loop bounds wave-uniform -> every lane active at every __shfl.
__global__ __launch_bounds__(256) void
conv1_gather(const int2* __restrict__ em, const int* __restrict__ start,
             const float* __restrict__ W1, const float* __restrict__ root1,
             const float* __restrict__ b1, uint* __restrict__ h16) {
    int lane = threadIdx.x & 63, wv = threadIdx.x >> 6;
    int n = blockIdx.x * 4 + wv;
    int e0 = start[n], e1 = start[n + 1];
    float ax = 0.f, ay = 0.f;
    for (int base = e0; base < e1; base += 64) {
        int m = e1 - base; if (m > 64) m = 64;
        int2 md = make_int2(0, 0);
        if (lane < m) md = em[base + lane];
        int i = 0;
        for (; i + 4 <= m; i += 4) {
            int p0 = __shfl(md.x, i + 0), p1 = __shfl(md.x, i + 1);
            int p2 = __shfl(md.x, i + 2), p3 = __shfl(md.x, i + 3);
            float w0 = __int_as_float(__shfl(md.y, i + 0));
            float w1 = __int_as_float(__shfl(md.y, i + 1));
            float w2 = __int_as_float(__shfl(md.y, i + 2));
            float w3 = __int_as_float(__shfl(md.y, i + 3));
            float2 v0 = ((const float2*)(W1 + ((size_t)(p0 >> 16) * N_NODES + (p0 & 0xFFFF)) * H_DIM))[lane];
            float2 v1 = ((const float2*)(W1 + ((size_t)(p1 >> 16) * N_NODES + (p1 & 0xFFFF)) * H_DIM))[lane];
            float2 v2 = ((const float2*)(W1 + ((size_t)(p2 >> 16) * N_NODES + (p2 & 0xFFFF)) * H_DIM))[lane];
            float2 v3 = ((const float2*)(W1 + ((size_t)(p3 >> 16) * N_NODES + (p3 & 0xFFFF)) * H_DIM))[lane];
            ax += w0 * v0.x + w1 * v1.x + w2 * v2.x + w3 * v3.x;
            ay += w0 * v0.y + w1 * v1.y + w2 * v2.y + w3 * v3.y;
        }
        for (; i < m; i++) {
            int p = __shfl(md.x, i);
            float w = __int_as_float(__shfl(md.y, i));
            float2 v = ((const float2*)(W1 + ((size_t)(p >> 16) * N_NODES + (p & 0xFFFF)) * H_DIM))[lane];
            ax += w * v.x; ay += w * v.y;
        }
    }
    float2 rt = ((const float2*)root1)[(size_t)n * 64 + lane];
    float2 bb = ((const float2*)b1)[lane];
    ax = fmaxf(ax + rt.x + bb.x, 0.f);
    ay = fmaxf(ay + rt.y + bb.y, 0.f);
    h16[(size_t)n * 64 + lane] = pack_bf16(ax, ay);
}

// ---------------- zgemm: Z[r] = h @ W2[r] (bf16), out = h @ root2 + b2 ---------
__global__ __launch_bounds__(256) void
zgemm(const uint* __restrict__ h16, const ushort* __restrict__ w2t,
      const float* __restrict__ b2, ushort* __restrict__ zb, float* __restrict__ out) {
    __shared__ uint ldsA[4096];   // 64 rows x 256B swizzled
    __shared__ uint ldsB[4096];
    int t = threadIdx.x, lane = t & 63, wv = t >> 6;
    int nbase = blockIdx.x * 64;
    for (int i = t; i < 4096; i += 256) {
        int row = i >> 6, cu = i & 63;
        int byte = (row * 256 + cu * 4) ^ ((row & 7) << 4);
        ldsA[byte >> 2] = h16[(size_t)(nbase + row) * 64 + cu];
    }
    const char* pA = (const char*)ldsA;
    const char* pB = (const char*)ldsB;
    int arow = wv * 16 + (lane & 15);
    int qk = (lane >> 4) * 16;
    for (int rr = 0; rr < 9; rr++) {
        __syncthreads();   // covers A staging and ldsB reuse
        const uint4* bsrc = (const uint4*)(w2t + (size_t)rr * 8192);
        ((uint4*)ldsB)[t]       = bsrc[t];
        ((uint4*)ldsB)[t + 256] = bsrc[t + 256];
        ((uint4*)ldsB)[t + 512] = bsrc[t + 512];
        ((uint4*)ldsB)[t + 768] = bsrc[t + 768];
        __syncthreads();
        f32x4 acc[4];
        #pragma unroll
        for (int ct = 0; ct < 4; ct++) acc[ct] = (f32x4){0.f, 0.f, 0.f, 0.f};
        #pragma unroll
        for (int ct = 0; ct < 4; ct++) {
            int bcol = ct * 16 + (lane & 15);
            #pragma unroll
            for (int kf = 0; kf < 4; kf++) {
                int abyte = (arow * 256 + kf * 64 + qk) ^ ((arow & 7) << 4);
                int bbyte = (bcol * 256 + kf * 64 + qk) ^ ((bcol & 7) << 4);
                bf16x8 a = *(const bf16x8*)(pA + abyte);
                bf16x8 b = *(const bf16x8*)(pB + bbyte);
                acc[ct] = __builtin_amdgcn_mfma_f32_16x16x32_bf16(a, b, acc[ct], 0, 0, 0);
            }
        }
        #pragma unroll
        for (int ct = 0; ct < 4; ct++) {
            int c = ct * 16 + (lane & 15);
            #pragma unroll
            for (int j = 0; j < 4; j++) {
                int n = nbase + wv * 16 + (lane >> 4) * 4 + j;
                if (rr < 8)
                    zb[((size_t)rr * N_NODES + n) * 64 + c] = (ushort)rne_bf16(acc[ct][j]);
                else
                    out[(size_t)n * 64 + c] = acc[ct][j] + b2[c];
            }
        }
    }
}

// ---------------- zgather: out[n] += sum_e w_e * Z[r_e, src_e, :] --------------
// 1 wave/node; halves process even/odd edges; ALL loop bounds wave-uniform so
// every lane is active at every __shfl (fix for R4's divergent-shuffle bug).
__global__ __launch_bounds__(256) void
zgather(const int2* __restrict__ em, const int* __restrict__ start,
        const uint* __restrict__ zb32, float* __restrict__ out) {
    int lane = threadIdx.x & 63, wv = threadIdx.x >> 6;
    int n = blockIdx.x * 4 + wv;
    int eg = lane >> 5, c2 = lane & 31;
    int e0 = start[n], e1 = start[n + 1];
    float ax = 0.f, ay = 0.f;
    for (int base = e0; base < e1; base += 64) {
        int m = e1 - base; if (m > 64) m = 64;
        int2 md = make_int2(0, 0);
        if (lane < m) md = em[base + lane];
        int i = 0;
        // main: 8 edges per wave-iteration (4 per half); trip count uniform
        for (; i + 8 <= m; i += 8) {
            int i0 = i + eg, i1 = i + eg + 2, i2 = i + eg + 4, i3 = i + eg + 6;
            int p0 = __shfl(md.x, i0), p1 = __shfl(md.x, i1);
            int p2 = __shfl(md.x, i2), p3 = __shfl(md.x, i3);
            float w0 = __int_as_float(__shfl(md.y, i0));
            float w1 = __int_as_float(__shfl(md.y, i1));
            float w2 = __int_as_float(__shfl(md.y, i2));
            float w3 = __int_as_float(__shfl(md.y, i3));
            uint z0 = zb32[((size_t)(p0 >> 16) * N_NODES + (p0 & 0xFFFF)) * 32 + c2];
            uint z1 = zb32[((size_t)(p1 >> 16) * N_NODES + (p1 & 0xFFFF)) * 32 + c2];
            uint z2 = zb32[((size_t)(p2 >> 16) * N_NODES + (p2 & 0xFFFF)) * 32 + c2];
            uint z3 = zb32[((size_t)(p3 >> 16) * N_NODES + (p3 & 0xFFFF)) * 32 + c2];
            ax += w0 * bf_lo(z0) + w1 * bf_lo(z1) + w2 * bf_lo(z2) + w3 * bf_lo(z3);
            ay += w0 * bf_hi(z0) + w1 * bf_hi(z1) + w2 * bf_hi(z2) + w3 * bf_hi(z3);
        }
        // tail: 2 edges per wave-iteration (1 per half); uniform bound, shuffles
        // executed by all lanes; contribution predicated per half.
        for (; i < m; i += 2) {
            int ii = i + eg;
            int srcl = (ii < m) ? ii : 0;
            int p = __shfl(md.x, srcl);
            float w = __int_as_float(__shfl(md.y, srcl));
            if (ii < m) {
                uint zv = zb32[((size_t)(p >> 16) * N_NODES + (p & 0xFFFF)) * 32 + c2];
                ax += w * bf_lo(zv);
                ay += w * bf_hi(zv);
            }
        }
    }
    ax += __shfl_xor(ax, 32);
    ay += __shfl_xor(ay, 32);
    if (eg == 0) {
        float2* o = (float2*)out + (size_t)n * 32 + c2;
        float2 v = *o;
        v.x += ax; v.y += ay;
        *o = v;
    }
}

extern "C" void kernel_launch(void* const* d_in, const int* in_sizes, int n_in,
                              void* d_out, int out_size, void* d_ws, size_t ws_size,
                              hipStream_t stream) {
    const int*   ei    = (const int*)d_in[0];
    const int*   et    = (const int*)d_in[1];
    const float* W1    = (const float*)d_in[2];
    const float* root1 = (const float*)d_in[3];
    const float* b1    = (const float*)d_in[4];
    const float* W2    = (const float*)d_in[5];
    const float* root2 = (const float*)d_in[6];
    const float* b2    = (const float*)d_in[7];
    float* out = (float*)d_out;

    // ws layout: [cnt NR][deg N][cursor N] zeroed together, then the rest
    int*    cnt    = (int*)d_ws;                    // NR
    int*    deg    = cnt + NR;                      // N
    int*    cursor = deg + N_NODES;                 // N
    int*    start  = cursor + N_NODES;              // N+16
    int2*   em     = (int2*)(start + N_NODES + 16); // E int2 (8B-aligned)
    uint*   h16    = (uint*)(em + N_EDGES);         // N*64
    ushort* w2t    = (ushort*)(h16 + (size_t)N_NODES * 64);   // 9*8192
    ushort* zb     = w2t + 9 * 8192;                // 8*N*64 bf16 = 41 MB

    hipMemsetAsync(cnt, 0, (size_t)(NR + 2 * N_NODES) * sizeof(int), stream);

    count_kernel  <<<(N_EDGES + 255) / 256, 256, 0, stream>>>(ei, et, cnt, deg);
    convert_w2    <<<(9 * C_DIM * H_DIM + 255) / 256, 256, 0, stream>>>(W2, root2, w2t);
    scan_all      <<<1, 1024, 0, stream>>>(deg, start);
    reorder_kernel<<<(N_EDGES + 255) / 256, 256, 0, stream>>>(ei, et, start, cnt, cursor, em);
    conv1_gather  <<<N_NODES / 4, 256, 0, stream>>>(em, start, W1, root1, b1, h16);
    zgemm         <<<N_NODES / 64, 256, 0, stream>>>(h16, w2t, b2, zb, out);
    zgather       <<<N_NODES / 4, 256, 0, stream>>>(em, start, (const uint*)zb, out);
}

// Round 9
// 442.925 us; speedup vs baseline: 5.8122x; 1.0085x over previous
//
#include <hip/hip_runtime.h>

#define N_NODES 40000
#define N_EDGES 640000
#define N_REL   8
#define H_DIM   128
#define C_DIM   64
#define NR      (N_NODES * N_REL)
#define SCAN_ITEMS 40   // 1024 * 40 = 40960 >= N_NODES

typedef __attribute__((ext_vector_type(8))) short bf16x8;
typedef __attribute__((ext_vector_type(4))) float f32x4;

__device__ inline uint rne_bf16(float x) {
    uint u = __float_as_uint(x);
    return (u + 0x7FFFu + ((u >> 16) & 1u)) >> 16;
}
__device__ inline uint pack_bf16(float x, float y) {   // x -> low half
    return rne_bf16(x) | (rne_bf16(y) << 16);
}
__device__ inline float bf_lo(uint v) { return __uint_as_float(v << 16); }
__device__ inline float bf_hi(uint v) { return __uint_as_float(v & 0xFFFF0000u); }

// ---------------- counts: per-(dst,rel) + per-dst degree ----------------
__global__ void count_kernel(const int* __restrict__ ei,
                             const int* __restrict__ et,
                             int* __restrict__ cnt, int* __restrict__ deg) {
    int e = blockIdx.x * blockDim.x + threadIdx.x;
    if (e < N_EDGES) {
        int dst = ei[N_EDGES + e];
        atomicAdd(&cnt[dst * N_REL + et[e]], 1);
        atomicAdd(&deg[dst], 1);
    }
}

// ---------------- single-block exclusive scan over node degrees ----------------
__global__ __launch_bounds__(1024) void
scan_all(const int* __restrict__ deg, int* __restrict__ start) {
    __shared__ int lds[1024];
    int t = threadIdx.x;
    int v[SCAN_ITEMS]; int s = 0;
    #pragma unroll
    for (int j = 0; j < SCAN_ITEMS; j++) {
        int idx = t * SCAN_ITEMS + j;
        v[j] = (idx < N_NODES) ? deg[idx] : 0;
        s += v[j];
    }
    lds[t] = s; __syncthreads();
    int x = s;
    for (int off = 1; off < 1024; off <<= 1) {
        int y = (t >= off) ? lds[t - off] : 0;
        __syncthreads();
        x += y; lds[t] = x;
        __syncthreads();
    }
    int excl = x - s;
    #pragma unroll
    for (int j = 0; j < SCAN_ITEMS; j++) {
        int idx = t * SCAN_ITEMS + j;
        if (idx < N_NODES) start[idx] = excl;
        excl += v[j];
    }
    if (t == 1023) start[N_NODES] = x;   // == N_EDGES
}

// ---------------- reorder: em[o] = (src|r<<16, bits(1/cnt[dst,r])) ----------------
__global__ void reorder_kernel(const int* __restrict__ ei, const int* __restrict__ et,
                               const int* __restrict__ start, const int* __restrict__ cnt,
                               int* __restrict__ cursor, int2* __restrict__ em) {
    int e = blockIdx.x * blockDim.x + threadIdx.x;
    if (e < N_EDGES) {
        int r = et[e];
        int dst = ei[N_EDGES + e];
        int pos = atomicAdd(&cursor[dst], 1);
        em[start[dst] + pos] =
            make_int2(ei[e] | (r << 16),
                      __float_as_int(1.0f / (float)cnt[dst * N_REL + r]));
    }
}

// ---------------- w2t: pre-swizzled bf16 [9][c=64][k=128] (r=8 is root2) -------
__global__ void convert_w2(const float* __restrict__ W2, const float* __restrict__ root2,
                           ushort* __restrict__ w2t) {
    int i = blockIdx.x * 256 + threadIdx.x;    // 9*64*128 = 73728
    if (i >= 9 * C_DIM * H_DIM) return;
    int k = i & 127; int c = (i >> 7) & 63; int r = i >> 13;
    float v = (r < 8) ? W2[((size_t)r * H_DIM + k) * C_DIM + c]
                      : root2[(size_t)k * C_DIM + c];
    int byte = (c * 256 + k * 2) ^ ((c & 7) << 4);   // XOR-swizzle (T2)
    w2t[(size_t)r * 8192 + (byte >> 1)] = (ushort)rne_bf16(v);
}

// ---------------- conv1: 1 wave/node, half-wave float4, 8 rows in flight -------
// h[n] = relu( sum_e w_e * W1[r_e, src_e, :] + root1[n] + b1 )
// Half-wave eg (32 lanes x float4 = 512B) covers a full row; halves process
// even/odd edges. ALL loop bounds wave-uniform -> every lane active at shuffles.
__global__ __launch_bounds__(256) void
conv1_gather(const int2* __restrict__ em, const int* __restrict__ start,
             const float* __restrict__ W1, const float* __restrict__ root1,
             const float* __restrict__ b1, uint* __restrict__ h16) {
    int lane = threadIdx.x & 63, wv = threadIdx.x >> 6;
    int eg = lane >> 5, q = lane & 31;     // edge-group, float4 index in row
    int n = blockIdx.x * 4 + wv;
    int e0 = start[n], e1 = start[n + 1];
    float4 acc = make_float4(0.f, 0.f, 0.f, 0.f);
    for (int base = e0; base < e1; base += 64) {
        int m = e1 - base; if (m > 64) m = 64;
        int2 md = make_int2(0, 0);
        if (lane < m) md = em[base + lane];
        int i = 0;
        // main: 8 edges per wave-iteration (4 per half), uniform trip count
        for (; i + 8 <= m; i += 8) {
            int i0 = i + eg, i1 = i + eg + 2, i2 = i + eg + 4, i3 = i + eg + 6;
            int p0 = __shfl(md.x, i0), p1 = __shfl(md.x, i1);
            int p2 = __shfl(md.x, i2), p3 = __shfl(md.x, i3);
            float w0 = __int_as_float(__shfl(md.y, i0));
            float w1 = __int_as_float(__shfl(md.y, i1));
            float w2 = __int_as_float(__shfl(md.y, i2));
            float w3 = __int_as_float(__shfl(md.y, i3));
            float4 v0 = ((const float4*)(W1 + ((size_t)(p0 >> 16) * N_NODES + (p0 & 0xFFFF)) * H_DIM))[q];
            float4 v1 = ((const float4*)(W1 + ((size_t)(p1 >> 16) * N_NODES + (p1 & 0xFFFF)) * H_DIM))[q];
            float4 v2 = ((const float4*)(W1 + ((size_t)(p2 >> 16) * N_NODES + (p2 & 0xFFFF)) * H_DIM))[q];
            float4 v3 = ((const float4*)(W1 + ((size_t)(p3 >> 16) * N_NODES + (p3 & 0xFFFF)) * H_DIM))[q];
            acc.x += w0 * v0.x + w1 * v1.x + w2 * v2.x + w3 * v3.x;
            acc.y += w0 * v0.y + w1 * v1.y + w2 * v2.y + w3 * v3.y;
            acc.z += w0 * v0.z + w1 * v1.z + w2 * v2.z + w3 * v3.z;
            acc.w += w0 * v0.w + w1 * v1.w + w2 * v2.w + w3 * v3.w;
        }
        // tail: 2 edges per wave-iteration (1 per half); clamp shuffle source,
        // predicate the contribution only.
        for (; i < m; i += 2) {
            int ii = i + eg;
            int srcl = (ii < m) ? ii : 0;
            int p = __shfl(md.x, srcl);
            float w = __int_as_float(__shfl(md.y, srcl));
            if (ii < m) {
                float4 v = ((const float4*)(W1 + ((size_t)(p >> 16) * N_NODES + (p & 0xFFFF)) * H_DIM))[q];
                acc.x += w * v.x; acc.y += w * v.y;
                acc.z += w * v.z; acc.w += w * v.w;
            }
        }
    }
    // combine halves (both end up with the full sum)
    acc.x += __shfl_xor(acc.x, 32);
    acc.y += __shfl_xor(acc.y, 32);
    acc.z += __shfl_xor(acc.z, 32);
    acc.w += __shfl_xor(acc.w, 32);
    if (eg == 0) {
        float4 rt = ((const float4*)root1)[(size_t)n * 32 + q];
        float4 bb = ((const float4*)b1)[q];
        float cx = fmaxf(acc.x + rt.x + bb.x, 0.f);
        float cy = fmaxf(acc.y + rt.y + bb.y, 0.f);
        float cz = fmaxf(acc.z + rt.z + bb.z, 0.f);
        float cw = fmaxf(acc.w + rt.w + bb.w, 0.f);
        uint2 o; o.x = pack_bf16(cx, cy); o.y = pack_bf16(cz, cw);
        ((uint2*)h16)[(size_t)n * 32 + q] = o;
    }
}

// ---------------- zgemm: Z[r] = h @ W2[r] (bf16), out = h @ root2 + b2 ---------
__global__ __launch_bounds__(256) void
zgemm(const uint* __restrict__ h16, const ushort* __restrict__ w2t,
      const float* __restrict__ b2, ushort* __restrict__ zb, float* __restrict__ out) {
    __shared__ uint ldsA[4096];   // 64 rows x 256B swizzled
    __shared__ uint ldsB[4096];
    int t = threadIdx.x, lane = t & 63, wv = t >> 6;
    int nbase = blockIdx.x * 64;
    for (int i = t; i < 4096; i += 256) {
        int row = i >> 6, cu = i & 63;
        int byte = (row * 256 + cu * 4) ^ ((row & 7) << 4);
        ldsA[byte >> 2] = h16[(size_t)(nbase + row) * 64 + cu];
    }
    const char* pA = (const char*)ldsA;
    const char* pB = (const char*)ldsB;
    int arow = wv * 16 + (lane & 15);
    int qk = (lane >> 4) * 16;
    for (int rr = 0; rr < 9; rr++) {
        __syncthreads();   // covers A staging and ldsB reuse
        const uint4* bsrc = (const uint4*)(w2t + (size_t)rr * 8192);
        ((uint4*)ldsB)[t]       = bsrc[t];
        ((uint4*)ldsB)[t + 256] = bsrc[t + 256];
        ((uint4*)ldsB)[t + 512] = bsrc[t + 512];
        ((uint4*)ldsB)[t + 768] = bsrc[t + 768];
        __syncthreads();
        f32x4 acc[4];
        #pragma unroll
        for (int ct = 0; ct < 4; ct++) acc[ct] = (f32x4){0.f, 0.f, 0.f, 0.f};
        #pragma unroll
        for (int ct = 0; ct < 4; ct++) {
            int bcol = ct * 16 + (lane & 15);
            #pragma unroll
            for (int kf = 0; kf < 4; kf++) {
                int abyte = (arow * 256 + kf * 64 + qk) ^ ((arow & 7) << 4);
                int bbyte = (bcol * 256 + kf * 64 + qk) ^ ((bcol & 7) << 4);
                bf16x8 a = *(const bf16x8*)(pA + abyte);
                bf16x8 b = *(const bf16x8*)(pB + bbyte);
                acc[ct] = __builtin_amdgcn_mfma_f32_16x16x32_bf16(a, b, acc[ct], 0, 0, 0);
            }
        }
        #pragma unroll
        for (int ct = 0; ct < 4; ct++) {
            int c = ct * 16 + (lane & 15);
            #pragma unroll
            for (int j = 0; j < 4; j++) {
                int n = nbase + wv * 16 + (lane >> 4) * 4 + j;
                if (rr < 8)
                    zb[((size_t)rr * N_NODES + n) * 64 + c] = (ushort)rne_bf16(acc[ct][j]);
                else
                    out[(size_t)n * 64 + c] = acc[ct][j] + b2[c];
            }
        }
    }
}

// ---------------- zgather: out[n] += sum_e w_e * Z[r_e, src_e, :] --------------
// 1 wave/node; halves process even/odd edges; 8 rows in flight in main loop.
// ALL loop bounds wave-uniform; tail clamps shuffle source, predicates math.
__global__ __launch_bounds__(256) void
zgather(const int2* __restrict__ em, const int* __restrict__ start,
        const uint* __restrict__ zb32, float* __restrict__ out) {
    int lane = threadIdx.x & 63, wv = threadIdx.x >> 6;
    int n = blockIdx.x * 4 + wv;
    int eg = lane >> 5, c2 = lane & 31;
    int e0 = start[n], e1 = start[n + 1];
    float ax = 0.f, ay = 0.f;
    for (int base = e0; base < e1; base += 64) {
        int m = e1 - base; if (m > 64) m = 64;
        int2 md = make_int2(0, 0);
        if (lane < m) md = em[base + lane];
        int i = 0;
        // main: 16 edges per wave-iteration (8 per half)
        for (; i + 16 <= m; i += 16) {
            #pragma unroll
            for (int u = 0; u < 2; u++) {
                int j0 = i + u * 8 + eg, j1 = j0 + 2, j2 = j0 + 4, j3 = j0 + 6;
                int p0 = __shfl(md.x, j0), p1 = __shfl(md.x, j1);
                int p2 = __shfl(md.x, j2), p3 = __shfl(md.x, j3);
                float w0 = __int_as_float(__shfl(md.y, j0));
                float w1 = __int_as_float(__shfl(md.y, j1));
                float w2 = __int_as_float(__shfl(md.y, j2));
                float w3 = __int_as_float(__shfl(md.y, j3));
                uint z0 = zb32[((size_t)(p0 >> 16) * N_NODES + (p0 & 0xFFFF)) * 32 + c2];
                uint z1 = zb32[((size_t)(p1 >> 16) * N_NODES + (p1 & 0xFFFF)) * 32 + c2];
                uint z2 = zb32[((size_t)(p2 >> 16) * N_NODES + (p2 & 0xFFFF)) * 32 + c2];
                uint z3 = zb32[((size_t)(p3 >> 16) * N_NODES + (p3 & 0xFFFF)) * 32 + c2];
                ax += w0 * bf_lo(z0) + w1 * bf_lo(z1) + w2 * bf_lo(z2) + w3 * bf_lo(z3);
                ay += w0 * bf_hi(z0) + w1 * bf_hi(z1) + w2 * bf_hi(z2) + w3 * bf_hi(z3);
            }
        }
        // mid: 8 edges (4 per half)
        for (; i + 8 <= m; i += 8) {
            int j0 = i + eg, j1 = j0 + 2, j2 = j0 + 4, j3 = j0 + 6;
            int p0 = __shfl(md.x, j0), p1 = __shfl(md.x, j1);
            int p2 = __shfl(md.x, j2), p3 = __shfl(md.x, j3);
            float w0 = __int_as_float(__shfl(md.y, j0));
            float w1 = __int_as_float(__shfl(md.y, j1));
            float w2 = __int_as_float(__shfl(md.y, j2));
            float w3 = __int_as_float(__shfl(md.y, j3));
            uint z0 = zb32[((size_t)(p0 >> 16) * N_NODES + (p0 & 0xFFFF)) * 32 + c2];
            uint z1 = zb32[((size_t)(p1 >> 16) * N_NODES + (p1 & 0xFFFF)) * 32 + c2];
            uint z2 = zb32[((size_t)(p2 >> 16) * N_NODES + (p2 & 0xFFFF)) * 32 + c2];
            uint z3 = zb32[((size_t)(p3 >> 16) * N_NODES + (p3 & 0xFFFF)) * 32 + c2];
            ax += w0 * bf_lo(z0) + w1 * bf_lo(z1) + w2 * bf_lo(z2) + w3 * bf_lo(z3);
            ay += w0 * bf_hi(z0) + w1 * bf_hi(z1) + w2 * bf_hi(z2) + w3 * bf_hi(z3);
        }
        // tail: 2 edges per wave-iteration (1 per half)
        for (; i < m; i += 2) {
            int ii = i + eg;
            int srcl = (ii < m) ? ii : 0;
            int p = __shfl(md.x, srcl);
            float w = __int_as_float(__shfl(md.y, srcl));
            if (ii < m) {
                uint zv = zb32[((size_t)(p >> 16) * N_NODES + (p & 0xFFFF)) * 32 + c2];
                ax += w * bf_lo(zv);
                ay += w * bf_hi(zv);
            }
        }
    }
    ax += __shfl_xor(ax, 32);
    ay += __shfl_xor(ay, 32);
    if (eg == 0) {
        float2* o = (float2*)out + (size_t)n * 32 + c2;
        float2 v = *o;
        v.x += ax; v.y += ay;
        *o = v;
    }
}

extern "C" void kernel_launch(void* const* d_in, const int* in_sizes, int n_in,
                              void* d_out, int out_size, void* d_ws, size_t ws_size,
                              hipStream_t stream) {
    const int*   ei    = (const int*)d_in[0];
    const int*   et    = (const int*)d_in[1];
    const float* W1    = (const float*)d_in[2];
    const float* root1 = (const float*)d_in[3];
    const float* b1    = (const float*)d_in[4];
    const float* W2    = (const float*)d_in[5];
    const float* root2 = (const float*)d_in[6];
    const float* b2    = (const float*)d_in[7];
    float* out = (float*)d_out;

    // ws layout: [cnt NR][deg N][cursor N] zeroed together, then the rest
    int*    cnt    = (int*)d_ws;                    // NR
    int*    deg    = cnt + NR;                      // N
    int*    cursor = deg + N_NODES;                 // N
    int*    start  = cursor + N_NODES;              // N+16
    int2*   em     = (int2*)(start + N_NODES + 16); // E int2 (8B-aligned)
    uint*   h16    = (uint*)(em + N_EDGES);         // N*64
    ushort* w2t    = (ushort*)(h16 + (size_t)N_NODES * 64);   // 9*8192
    ushort* zb     = w2t + 9 * 8192;                // 8*N*64 bf16 = 41 MB

    hipMemsetAsync(cnt, 0, (size_t)(NR + 2 * N_NODES) * sizeof(int), stream);

    count_kernel  <<<(N_EDGES + 255) / 256, 256, 0, stream>>>(ei, et, cnt, deg);
    convert_w2    <<<(9 * C_DIM * H_DIM + 255) / 256, 256, 0, stream>>>(W2, root2, w2t);
    scan_all      <<<1, 1024, 0, stream>>>(deg, start);
    reorder_kernel<<<(N_EDGES + 255) / 256, 256, 0, stream>>>(ei, et, start, cnt, cursor, em);
    conv1_gather  <<<N_NODES / 4, 256, 0, stream>>>(em, start, W1, root1, b1, h16);
    zgemm         <<<N_NODES / 64, 256, 0, stream>>>(h16, w2t, b2, zb, out);
    zgather       <<<N_NODES / 4, 256, 0, stream>>>(em, start, (const uint*)zb, out);
}

// Round 10
// 369.567 us; speedup vs baseline: 6.9659x; 1.1985x over previous
//
#include <hip/hip_runtime.h>

#define N_NODES 40000
#define N_EDGES 640000
#define N_REL   8
#define H_DIM   128
#define C_DIM   64
#define NR      (N_NODES * N_REL)        // 320000 segments
#define SCAN_NB ((NR + 1023) / 1024)     // 313 scan blocks

typedef __attribute__((ext_vector_type(8))) short bf16x8;
typedef __attribute__((ext_vector_type(4))) float f32x4;

__device__ inline uint rne_bf16(float x) {
    uint u = __float_as_uint(x);
    return (u + 0x7FFFu + ((u >> 16) & 1u)) >> 16;
}
__device__ inline uint pack_bf16(float x, float y) {   // x -> low half
    return rne_bf16(x) | (rne_bf16(y) << 16);
}
__device__ inline float bf_lo(uint v) { return __uint_as_float(v << 16); }
__device__ inline float bf_hi(uint v) { return __uint_as_float(v & 0xFFFF0000u); }

// ---------------- count + rank: rank[e] = position within segment ----------------
__global__ void count_rank(const int* __restrict__ ei, const int* __restrict__ et,
                           int* __restrict__ cnt, int* __restrict__ rank) {
    int e = blockIdx.x * blockDim.x + threadIdx.x;
    if (e < N_EDGES) {
        int seg = ei[N_EDGES + e] * N_REL + et[e];
        rank[e] = atomicAdd(&cnt[seg], 1);     // old value = rank; cnt ends = count
    }
}

// ---------------- multi-block exclusive scan over NR (coalesced) ----------------
__global__ void scanA(const int* __restrict__ cnt, int* __restrict__ segbase,
                      int* __restrict__ bsum) {
    __shared__ int lds[256];
    int base = blockIdx.x * 1024;
    int t = threadIdx.x;
    int v[4]; int s = 0;
    #pragma unroll
    for (int j = 0; j < 4; j++) {              // 4 consecutive ints per thread
        int idx = base + t * 4 + j;
        v[j] = (idx < NR) ? cnt[idx] : 0;
        s += v[j];
    }
    lds[t] = s; __syncthreads();
    int x = s;
    #pragma unroll
    for (int off = 1; off < 256; off <<= 1) {
        int y = (t >= off) ? lds[t - off] : 0;
        __syncthreads();
        x += y; lds[t] = x;
        __syncthreads();
    }
    int excl = x - s;
    #pragma unroll
    for (int j = 0; j < 4; j++) {
        int idx = base + t * 4 + j;
        if (idx < NR) segbase[idx] = excl;
        excl += v[j];
    }
    if (t == 255) bsum[blockIdx.x] = x;
}

__global__ __launch_bounds__(512) void
scanB(int* __restrict__ bsum, int* __restrict__ segbase) {
    __shared__ int lds[512];
    int t = threadIdx.x;
    int v = (t < SCAN_NB) ? bsum[t] : 0;
    lds[t] = v; __syncthreads();
    int x = v;
    for (int off = 1; off < 512; off <<= 1) {
        int y = (t >= off) ? lds[t - off] : 0;
        __syncthreads();
        x += y; lds[t] = x;
        __syncthreads();
    }
    if (t < SCAN_NB) bsum[t] = x - v;          // exclusive block offset
    if (t == 511) segbase[NR] = x;             // total == N_EDGES (sentinel)
}

__global__ void scanC(int* __restrict__ segbase, const int* __restrict__ bsum) {
    int idx = blockIdx.x * blockDim.x + threadIdx.x;
    if (idx < NR) segbase[idx] += bsum[idx >> 10];
}

// ---------------- scatter (atomic-free): em[segbase[seg]+rank[e]] ----------------
__global__ void scatter_kernel(const int* __restrict__ ei, const int* __restrict__ et,
                               const int* __restrict__ segbase, const int* __restrict__ cnt,
                               const int* __restrict__ rank, int2* __restrict__ em) {
    int e = blockIdx.x * blockDim.x + threadIdx.x;
    if (e < N_EDGES) {
        int r = et[e];
        int seg = ei[N_EDGES + e] * N_REL + r;
        int o = segbase[seg] + rank[e];
        em[o] = make_int2(ei[e] | (r << 16),
                          __float_as_int(1.0f / (float)cnt[seg]));
    }
}

// ---------------- w2t: pre-swizzled bf16 [9][c=64][k=128] (r=8 is root2) -------
__global__ void convert_w2(const float* __restrict__ W2, const float* __restrict__ root2,
                           ushort* __restrict__ w2t) {
    int i = blockIdx.x * 256 + threadIdx.x;    // 9*64*128 = 73728
    if (i >= 9 * C_DIM * H_DIM) return;
    int k = i & 127; int c = (i >> 7) & 63; int r = i >> 13;
    float v = (r < 8) ? W2[((size_t)r * H_DIM + k) * C_DIM + c]
                      : root2[(size_t)k * C_DIM + c];
    int byte = (c * 256 + k * 2) ^ ((c & 7) << 4);   // XOR-swizzle (T2)
    w2t[(size_t)r * 8192 + (byte >> 1)] = (ushort)rne_bf16(v);
}

// ---------------- conv1: 1 wave/node, half-wave float4, 8 rows in flight -------
// h[n] = relu( sum_e w_e * W1[r_e, src_e, :] + root1[n] + b1 )
__global__ __launch_bounds__(256) void
conv1_gather(const int2* __restrict__ em, const int* __restrict__ segbase,
             const float* __restrict__ W1, const float* __restrict__ root1,
             const float* __restrict__ b1, uint* __restrict__ h16) {
    int lane = threadIdx.x & 63, wv = threadIdx.x >> 6;
    int eg = lane >> 5, q = lane & 31;     // edge-group, float4 index in row
    int n = blockIdx.x * 4 + wv;
    int e0 = segbase[n * N_REL], e1 = segbase[n * N_REL + N_REL];
    float4 acc = make_float4(0.f, 0.f, 0.f, 0.f);
    for (int base = e0; base < e1; base += 64) {
        int m = e1 - base; if (m > 64) m = 64;
        int2 md = make_int2(0, 0);
        if (lane < m) md = em[base + lane];
        int i = 0;
        for (; i + 8 <= m; i += 8) {
            int i0 = i + eg, i1 = i + eg + 2, i2 = i + eg + 4, i3 = i + eg + 6;
            int p0 = __shfl(md.x, i0), p1 = __shfl(md.x, i1);
            int p2 = __shfl(md.x, i2), p3 = __shfl(md.x, i3);
            float w0 = __int_as_float(__shfl(md.y, i0));
            float w1 = __int_as_float(__shfl(md.y, i1));
            float w2 = __int_as_float(__shfl(md.y, i2));
            float w3 = __int_as_float(__shfl(md.y, i3));
            float4 v0 = ((const float4*)(W1 + ((size_t)(p0 >> 16) * N_NODES + (p0 & 0xFFFF)) * H_DIM))[q];
            float4 v1 = ((const float4*)(W1 + ((size_t)(p1 >> 16) * N_NODES + (p1 & 0xFFFF)) * H_DIM))[q];
            float4 v2 = ((const float4*)(W1 + ((size_t)(p2 >> 16) * N_NODES + (p2 & 0xFFFF)) * H_DIM))[q];
            float4 v3 = ((const float4*)(W1 + ((size_t)(p3 >> 16) * N_NODES + (p3 & 0xFFFF)) * H_DIM))[q];
            acc.x += w0 * v0.x + w1 * v1.x + w2 * v2.x + w3 * v3.x;
            acc.y += w0 * v0.y + w1 * v1.y + w2 * v2.y + w3 * v3.y;
            acc.z += w0 * v0.z + w1 * v1.z + w2 * v2.z + w3 * v3.z;
            acc.w += w0 * v0.w + w1 * v1.w + w2 * v2.w + w3 * v3.w;
        }
        for (; i < m; i += 2) {
            int ii = i + eg;
            int srcl = (ii < m) ? ii : 0;
            int p = __shfl(md.x, srcl);
            float w = __int_as_float(__shfl(md.y, srcl));
            if (ii < m) {
                float4 v = ((const float4*)(W1 + ((size_t)(p >> 16) * N_NODES + (p & 0xFFFF)) * H_DIM))[q];
                acc.x += w * v.x; acc.y += w * v.y;
                acc.z += w * v.z; acc.w += w * v.w;
            }
        }
    }
    acc.x += __shfl_xor(acc.x, 32);
    acc.y += __shfl_xor(acc.y, 32);
    acc.z += __shfl_xor(acc.z, 32);
    acc.w += __shfl_xor(acc.w, 32);
    if (eg == 0) {
        float4 rt = ((const float4*)root1)[(size_t)n * 32 + q];
        float4 bb = ((const float4*)b1)[q];
        float cx = fmaxf(acc.x + rt.x + bb.x, 0.f);
        float cy = fmaxf(acc.y + rt.y + bb.y, 0.f);
        float cz = fmaxf(acc.z + rt.z + bb.z, 0.f);
        float cw = fmaxf(acc.w + rt.w + bb.w, 0.f);
        uint2 o; o.x = pack_bf16(cx, cy); o.y = pack_bf16(cz, cw);
        ((uint2*)h16)[(size_t)n * 32 + q] = o;
    }
}

// ---------------- zgemm: Z[r] = h @ W2[r] (bf16), out = h @ root2 + b2 ---------
__global__ __launch_bounds__(256) void
zgemm(const uint* __restrict__ h16, const ushort* __restrict__ w2t,
      const float* __restrict__ b2, ushort* __restrict__ zb, float* __restrict__ out) {
    __shared__ uint ldsA[4096];   // 64 rows x 256B swizzled
    __shared__ uint ldsB[4096];
    int t = threadIdx.x, lane = t & 63, wv = t >> 6;
    int nbase = blockIdx.x * 64;
    for (int i = t; i < 4096; i += 256) {
        int row = i >> 6, cu = i & 63;
        int byte = (row * 256 + cu * 4) ^ ((row & 7) << 4);
        ldsA[byte >> 2] = h16[(size_t)(nbase + row) * 64 + cu];
    }
    const char* pA = (const char*)ldsA;
    const char* pB = (const char*)ldsB;
    int arow = wv * 16 + (lane & 15);
    int qk = (lane >> 4) * 16;
    for (int rr = 0; rr < 9; rr++) {
        __syncthreads();   // covers A staging and ldsB reuse
        const uint4* bsrc = (const uint4*)(w2t + (size_t)rr * 8192);
        ((uint4*)ldsB)[t]       = bsrc[t];
        ((uint4*)ldsB)[t + 256] = bsrc[t + 256];
        ((uint4*)ldsB)[t + 512] = bsrc[t + 512];
        ((uint4*)ldsB)[t + 768] = bsrc[t + 768];
        __syncthreads();
        f32x4 acc[4];
        #pragma unroll
        for (int ct = 0; ct < 4; ct++) acc[ct] = (f32x4){0.f, 0.f, 0.f, 0.f};
        #pragma unroll
        for (int ct = 0; ct < 4; ct++) {
            int bcol = ct * 16 + (lane & 15);
            #pragma unroll
            for (int kf = 0; kf < 4; kf++) {
                int abyte = (arow * 256 + kf * 64 + qk) ^ ((arow & 7) << 4);
                int bbyte = (bcol * 256 + kf * 64 + qk) ^ ((bcol & 7) << 4);
                bf16x8 a = *(const bf16x8*)(pA + abyte);
                bf16x8 b = *(const bf16x8*)(pB + bbyte);
                acc[ct] = __builtin_amdgcn_mfma_f32_16x16x32_bf16(a, b, acc[ct], 0, 0, 0);
            }
        }
        #pragma unroll
        for (int ct = 0; ct < 4; ct++) {
            int c = ct * 16 + (lane & 15);
            #pragma unroll
            for (int j = 0; j < 4; j++) {
                int n = nbase + wv * 16 + (lane >> 4) * 4 + j;
                if (rr < 8)
                    zb[((size_t)rr * N_NODES + n) * 64 + c] = (ushort)rne_bf16(acc[ct][j]);
                else
                    out[(size_t)n * 64 + c] = acc[ct][j] + b2[c];
            }
        }
    }
}

// ---------------- zgather: out[n] += sum_e w_e * Z[r_e, src_e, :] --------------
__global__ __launch_bounds__(256) void
zgather(const int2* __restrict__ em, const int* __restrict__ segbase,
        const uint* __restrict__ zb32, float* __restrict__ out) {
    int lane = threadIdx.x & 63, wv = threadIdx.x >> 6;
    int n = blockIdx.x * 4 + wv;
    int eg = lane >> 5, c2 = lane & 31;
    int e0 = segbase[n * N_REL], e1 = segbase[n * N_REL + N_REL];
    float ax = 0.f, ay = 0.f;
    for (int base = e0; base < e1; base += 64) {
        int m = e1 - base; if (m > 64) m = 64;
        int2 md = make_int2(0, 0);
        if (lane < m) md = em[base + lane];
        int i = 0;
        for (; i + 16 <= m; i += 16) {
            #pragma unroll
            for (int u = 0; u < 2; u++) {
                int j0 = i + u * 8 + eg, j1 = j0 + 2, j2 = j0 + 4, j3 = j0 + 6;
                int p0 = __shfl(md.x, j0), p1 = __shfl(md.x, j1);
                int p2 = __shfl(md.x, j2), p3 = __shfl(md.x, j3);
                float w0 = __int_as_float(__shfl(md.y, j0));
                float w1 = __int_as_float(__shfl(md.y, j1));
                float w2 = __int_as_float(__shfl(md.y, j2));
                float w3 = __int_as_float(__shfl(md.y, j3));
                uint z0 = zb32[((size_t)(p0 >> 16) * N_NODES + (p0 & 0xFFFF)) * 32 + c2];
                uint z1 = zb32[((size_t)(p1 >> 16) * N_NODES + (p1 & 0xFFFF)) * 32 + c2];
                uint z2 = zb32[((size_t)(p2 >> 16) * N_NODES + (p2 & 0xFFFF)) * 32 + c2];
                uint z3 = zb32[((size_t)(p3 >> 16) * N_NODES + (p3 & 0xFFFF)) * 32 + c2];
                ax += w0 * bf_lo(z0) + w1 * bf_lo(z1) + w2 * bf_lo(z2) + w3 * bf_lo(z3);
                ay += w0 * bf_hi(z0) + w1 * bf_hi(z1) + w2 * bf_hi(z2) + w3 * bf_hi(z3);
            }
        }
        for (; i + 8 <= m; i += 8) {
            int j0 = i + eg, j1 = j0 + 2, j2 = j0 + 4, j3 = j0 + 6;
            int p0 = __shfl(md.x, j0), p1 = __shfl(md.x, j1);
            int p2 = __shfl(md.x, j2), p3 = __shfl(md.x, j3);
            float w0 = __int_as_float(__shfl(md.y, j0));
            float w1 = __int_as_float(__shfl(md.y, j1));
            float w2 = __int_as_float(__shfl(md.y, j2));
            float w3 = __int_as_float(__shfl(md.y, j3));
            uint z0 = zb32[((size_t)(p0 >> 16) * N_NODES + (p0 & 0xFFFF)) * 32 + c2];
            uint z1 = zb32[((size_t)(p1 >> 16) * N_NODES + (p1 & 0xFFFF)) * 32 + c2];
            uint z2 = zb32[((size_t)(p2 >> 16) * N_NODES + (p2 & 0xFFFF)) * 32 + c2];
            uint z3 = zb32[((size_t)(p3 >> 16) * N_NODES + (p3 & 0xFFFF)) * 32 + c2];
            ax += w0 * bf_lo(z0) + w1 * bf_lo(z1) + w2 * bf_lo(z2) + w3 * bf_lo(z3);
            ay += w0 * bf_hi(z0) + w1 * bf_hi(z1) + w2 * bf_hi(z2) + w3 * bf_hi(z3);
        }
        for (; i < m; i += 2) {
            int ii = i + eg;
            int srcl = (ii < m) ? ii : 0;
            int p = __shfl(md.x, srcl);
            float w = __int_as_float(__shfl(md.y, srcl));
            if (ii < m) {
                uint zv = zb32[((size_t)(p >> 16) * N_NODES + (p & 0xFFFF)) * 32 + c2];
                ax += w * bf_lo(zv);
                ay += w * bf_hi(zv);
            }
        }
    }
    ax += __shfl_xor(ax, 32);
    ay += __shfl_xor(ay, 32);
    if (eg == 0) {
        float2* o = (float2*)out + (size_t)n * 32 + c2;
        float2 v = *o;
        v.x += ax; v.y += ay;
        *o = v;
    }
}

extern "C" void kernel_launch(void* const* d_in, const int* in_sizes, int n_in,
                              void* d_out, int out_size, void* d_ws, size_t ws_size,
                              hipStream_t stream) {
    const int*   ei    = (const int*)d_in[0];
    const int*   et    = (const int*)d_in[1];
    const float* W1    = (const float*)d_in[2];
    const float* root1 = (const float*)d_in[3];
    const float* b1    = (const float*)d_in[4];
    const float* W2    = (const float*)d_in[5];
    const float* root2 = (const float*)d_in[6];
    const float* b2    = (const float*)d_in[7];
    float* out = (float*)d_out;

    // ws layout
    int*    cnt     = (int*)d_ws;                   // NR
    int*    segbase = cnt + NR;                     // NR + 16 (sentinel at NR)
    int*    bsum    = segbase + NR + 16;            // 512
    int*    rank    = bsum + 512;                   // E
    int2*   em      = (int2*)(rank + N_EDGES);      // E int2 (8B-aligned)
    uint*   h16     = (uint*)(em + N_EDGES);        // N*64
    ushort* w2t     = (ushort*)(h16 + (size_t)N_NODES * 64);  // 9*8192
    ushort* zb      = w2t + 9 * 8192;               // 8*N*64 bf16 = 41 MB

    hipMemsetAsync(cnt, 0, (size_t)NR * sizeof(int), stream);

    count_rank    <<<(N_EDGES + 255) / 256, 256, 0, stream>>>(ei, et, cnt, rank);
    convert_w2    <<<(9 * C_DIM * H_DIM + 255) / 256, 256, 0, stream>>>(W2, root2, w2t);
    scanA         <<<SCAN_NB, 256, 0, stream>>>(cnt, segbase, bsum);
    scanB         <<<1, 512, 0, stream>>>(bsum, segbase);
    scanC         <<<(NR + 255) / 256, 256, 0, stream>>>(segbase, bsum);
    scatter_kernel<<<(N_EDGES + 255) / 256, 256, 0, stream>>>(ei, et, segbase, cnt, rank, em);
    conv1_gather  <<<N_NODES / 4, 256, 0, stream>>>(em, segbase, W1, root1, b1, h16);
    zgemm         <<<N_NODES / 64, 256, 0, stream>>>(h16, w2t, b2, zb, out);
    zgather       <<<N_NODES / 4, 256, 0, stream>>>(em, segbase, (const uint*)zb, out);
}